// Round 3
// baseline (311.874 us; speedup 1.0000x reference)
//
#include <hip/hip_runtime.h>

// Problem constants
#define B_   4
#define L_   4096
#define DM_  1024
#define DK_  128
#define OUT_K_OFF 2097152   // B*L*DK
#define OUT_V_OFF 4194304   // 2*B*L*DK

typedef __attribute__((ext_vector_type(4))) float f32x4;
typedef __attribute__((ext_vector_type(8))) short short8;

__device__ __forceinline__ unsigned short f2bf(float f) {
  union { float f; unsigned int u; } v; v.f = f;
  unsigned int u = v.u;
  u += 0x7FFFu + ((u >> 16) & 1u);   // RNE
  return (unsigned short)(u >> 16);
}

// async global->LDS, 16B per lane. LDS dest = wave-uniform base + lane*16.
#define ASYNC16(gsrc, ldst)                                                          \
  __builtin_amdgcn_global_load_lds(                                                  \
      (const __attribute__((address_space(1))) unsigned int*)(gsrc),                 \
      (__attribute__((address_space(3))) unsigned int*)(ldst), 16, 0, 0)

#define MFMA16(a, b, c) __builtin_amdgcn_mfma_f32_16x16x32_bf16((a), (b), (c), 0, 0, 0)

// ---------------------------------------------------------------------------
// Kernel 0: fp32 -> bf16 bulk convert (8 elems/thread, vectorized)
// ---------------------------------------------------------------------------
__global__ __launch_bounds__(256) void cvt_kernel(const float* __restrict__ s,
                                                  unsigned short* __restrict__ d,
                                                  int n8) {
  int i = blockIdx.x * 256 + threadIdx.x;
  if (i >= n8) return;
  const f32x4* p = (const f32x4*)(s + (size_t)i * 8);
  f32x4 a = p[0], b = p[1];
  short8 r;
  r[0] = (short)f2bf(a[0]); r[1] = (short)f2bf(a[1]);
  r[2] = (short)f2bf(a[2]); r[3] = (short)f2bf(a[3]);
  r[4] = (short)f2bf(b[0]); r[5] = (short)f2bf(b[1]);
  r[6] = (short)f2bf(b[2]); r[7] = (short)f2bf(b[3]);
  *(short8*)(d + (size_t)i * 8) = r;
}

// ---------------------------------------------------------------------------
// Kernel 1: projection GEMM.  out_tile[128 rows][128 cols] = x_tile @ W^T + b
// grid = (128 m-tiles, 3 weights). BK=64 bf16. LDS rows are 128B (8 x 16B
// chunks), XOR-swizzled with (row&7) to make ds_read_b128 conflict-free.
// wt==0 -> Q bf16 (ws); wt==1 -> K bf16 (ws) + K fp32 (out);
// wt==2 -> V fp32 (out) + V^T bf16 (ws, via LDS transpose).
// ---------------------------------------------------------------------------
__global__ __launch_bounds__(256) void proj_kernel(
    const unsigned short* __restrict__ xb,   // [B*L][1024] bf16
    const unsigned short* __restrict__ wb,   // [3][128][1024] bf16
    const float* __restrict__ bias_q, const float* __restrict__ bias_k,
    const float* __restrict__ bias_v,
    unsigned short* __restrict__ qb,         // [B*L][128] bf16
    unsigned short* __restrict__ kb,         // [B*L][128] bf16
    unsigned short* __restrict__ vt,         // [B][128][L] bf16 (V transposed)
    float* __restrict__ out) {
  __shared__ __align__(16) char smem[34816];  // A 16KB | B 16KB ; reused as T(128x272B)
  char* Alds = smem;
  char* Blds = smem + 16384;

  const int tid  = threadIdx.x;
  const int w    = tid >> 6;
  const int lane = tid & 63;
  const int lo4  = lane & 15, hi4 = lane >> 4;
  const int wm   = w >> 1, wn = w & 1;
  const int mt   = blockIdx.x;   // 0..127
  const int wt   = blockIdx.y;   // 0..2
  const int r0   = mt * 128;
  const unsigned short* wsrc = wb + (size_t)wt * (DK_ * DM_);

  f32x4 acc[4][4];
#pragma unroll
  for (int i = 0; i < 4; i++)
#pragma unroll
    for (int j = 0; j < 4; j++) acc[i][j] = (f32x4){0.f, 0.f, 0.f, 0.f};

  for (int kt = 0; kt < 16; ++kt) {
    const int kc0 = kt * 64;
    // stage x tile [128][64] and W tile [128][64]; pre-swizzled global source
#pragma unroll
    for (int j = 0; j < 4; ++j) {
      unsigned int o   = (unsigned)(w * 4096 + j * 1024 + lane * 16);
      unsigned int row = o >> 7;
      unsigned int cl  = ((o >> 4) & 7) ^ (row & 7);
      ASYNC16(xb + ((size_t)(r0 + row) * DM_ + kc0 + cl * 8), Alds + w * 4096 + j * 1024);
      ASYNC16(wsrc + ((size_t)row * DM_ + kc0 + cl * 8),      Blds + w * 4096 + j * 1024);
    }
    __syncthreads();
#pragma unroll
    for (int kk = 0; kk < 2; ++kk) {
      short8 af[4], bf[4];
#pragma unroll
      for (int mi = 0; mi < 4; mi++) {
        int row = wm * 64 + mi * 16 + lo4;
        int c   = kk * 4 + hi4;
        af[mi]  = *(const short8*)(Alds + row * 128 + (((c ^ (row & 7))) << 4));
      }
#pragma unroll
      for (int ni = 0; ni < 4; ni++) {
        int col = wn * 64 + ni * 16 + lo4;
        int c   = kk * 4 + hi4;
        bf[ni]  = *(const short8*)(Blds + col * 128 + (((c ^ (col & 7))) << 4));
      }
#pragma unroll
      for (int mi = 0; mi < 4; mi++)
#pragma unroll
        for (int ni = 0; ni < 4; ni++)
          acc[mi][ni] = MFMA16(af[mi], bf[ni], acc[mi][ni]);
    }
    __syncthreads();
  }

  const float* bias = (wt == 0) ? bias_q : (wt == 1) ? bias_k : bias_v;
  float bv4[4];
#pragma unroll
  for (int ni = 0; ni < 4; ni++) bv4[ni] = bias[wn * 64 + ni * 16 + lo4];

  const int b_idx = r0 >> 12;      // batch
  const int l0    = r0 & 4095;     // l within batch

  if (wt != 2) {
    unsigned short* dstb = (wt == 0) ? qb : kb;
#pragma unroll
    for (int mi = 0; mi < 4; mi++)
#pragma unroll
      for (int ni = 0; ni < 4; ni++)
#pragma unroll
        for (int reg = 0; reg < 4; reg++) {
          int r   = wm * 64 + mi * 16 + hi4 * 4 + reg;
          int c   = wn * 64 + ni * 16 + lo4;
          float v = acc[mi][ni][reg] + bv4[ni];
          dstb[(size_t)(r0 + r) * DK_ + c] = f2bf(v);
          if (wt == 1) out[OUT_K_OFF + (size_t)(r0 + r) * DK_ + c] = v;
        }
  } else {
    // V: fp32 to out, then LDS transpose -> vt (bf16, [d][l])
    char* T = smem;  // [128 d][272 bytes] (128 l bf16 + pad)
#pragma unroll
    for (int mi = 0; mi < 4; mi++)
#pragma unroll
      for (int ni = 0; ni < 4; ni++)
#pragma unroll
        for (int reg = 0; reg < 4; reg++) {
          int r   = wm * 64 + mi * 16 + hi4 * 4 + reg;
          int c   = wn * 64 + ni * 16 + lo4;
          float v = acc[mi][ni][reg] + bv4[ni];
          out[OUT_V_OFF + (size_t)(r0 + r) * DK_ + c] = v;
          *(unsigned short*)(T + c * 272 + r * 2) = f2bf(v);
        }
    __syncthreads();
#pragma unroll
    for (int i = 0; i < 8; ++i) {
      int q = tid + i * 256;
      int d = q >> 4, lg = q & 15;
      short8 s8 = *(const short8*)(T + d * 272 + lg * 16);
      *(short8*)(vt + ((size_t)(b_idx * DK_ + d) * L_ + l0 + lg * 8)) = s8;
    }
  }
}

// ---------------------------------------------------------------------------
// Kernel 2: flash attention. grid = (L/64 q-tiles, B). 4 waves x 16 q-rows.
// KV tile = 64 keys. K_lds[64][128]bf16 swizzled, Vt_lds[128][64]bf16 swizzled,
// P per-wave [16][64]bf16 swizzled. Online softmax in fp32 (exp2-based).
// output = NUM_BLOCKS(4) * attn @ V.
// ---------------------------------------------------------------------------
__global__ __launch_bounds__(256) void attn_kernel(
    const unsigned short* __restrict__ qb, const unsigned short* __restrict__ kb,
    const unsigned short* __restrict__ vt, float* __restrict__ out) {
  __shared__ __align__(16) char smem[40960];  // K 16KB | Vt 16KB | P 4x2KB
  char* Klds = smem;
  char* Vlds = smem + 16384;

  const int tid  = threadIdx.x;
  const int w    = tid >> 6;
  const int lane = tid & 63;
  const int lo4  = lane & 15, hi4 = lane >> 4;
  char* Plds = smem + 32768 + w * 2048;

  const int qt = blockIdx.x;  // 0..63
  const int b  = blockIdx.y;  // 0..3

  // Q fragments (16 rows x 128 d) held in registers for the whole kernel
  short8 aq[4];
  {
    const unsigned short* qp =
        qb + ((size_t)(b * L_ + qt * 64 + w * 16 + lo4) * DK_ + hi4 * 8);
#pragma unroll
    for (int kc = 0; kc < 4; kc++) aq[kc] = *(const short8*)(qp + kc * 32);
  }

  f32x4 o_acc[8];
#pragma unroll
  for (int dt = 0; dt < 8; dt++) o_acc[dt] = (f32x4){0.f, 0.f, 0.f, 0.f};
  float m[4]  = {-__builtin_inff(), -__builtin_inff(), -__builtin_inff(), -__builtin_inff()};
  float ls[4] = {0.f, 0.f, 0.f, 0.f};
  const float SC = 0.08838834764831845f * 1.4426950408889634f;  // 1/sqrt(128)*log2(e)

  for (int t = 0; t < 64; ++t) {
    // stage K tile (64x128) and Vt tile (128x64), both bf16 swizzled
#pragma unroll
    for (int j = 0; j < 4; ++j) {
      unsigned int o = (unsigned)(w * 1024 + j * 4096 + lane * 16);
      unsigned int krow = o >> 8;
      unsigned int kcl  = ((o >> 4) & 15) ^ (krow & 7);
      ASYNC16(kb + ((size_t)(b * L_ + t * 64 + krow) * DK_ + kcl * 8),
              Klds + w * 1024 + j * 4096);
      unsigned int d   = o >> 7;
      unsigned int vcl = ((o >> 4) & 7) ^ (d & 7);
      ASYNC16(vt + ((size_t)(b * DK_ + d) * L_ + t * 64 + vcl * 8),
              Vlds + w * 1024 + j * 4096);
    }
    __syncthreads();

    // S = Q K^T  (4 key-subtiles of 16)
    f32x4 s[4];
#pragma unroll
    for (int st = 0; st < 4; st++) s[st] = (f32x4){0.f, 0.f, 0.f, 0.f};
#pragma unroll
    for (int st = 0; st < 4; st++) {
      int key = st * 16 + lo4;
#pragma unroll
      for (int kc = 0; kc < 4; kc++) {
        int c = kc * 4 + hi4;
        short8 bkf = *(const short8*)(Klds + key * 256 + ((c ^ (key & 7)) << 4));
        s[st] = MFMA16(aq[kc], bkf, s[st]);
      }
    }

    // online softmax (rows = hi4*4+reg, lane owns cols st*16+lo4)
#pragma unroll
    for (int reg = 0; reg < 4; reg++) {
      float pm = fmaxf(fmaxf(s[0][reg], s[1][reg]), fmaxf(s[2][reg], s[3][reg]));
      pm = fmaxf(pm, __shfl_xor(pm, 1));
      pm = fmaxf(pm, __shfl_xor(pm, 2));
      pm = fmaxf(pm, __shfl_xor(pm, 4));
      pm = fmaxf(pm, __shfl_xor(pm, 8));
      pm *= SC;
      float mn   = fmaxf(m[reg], pm);
      float corr = exp2f(m[reg] - mn);
      m[reg]     = mn;
      float ps   = 0.f;
      int   r    = hi4 * 4 + reg;
#pragma unroll
      for (int st = 0; st < 4; st++) {
        float p = exp2f(s[st][reg] * SC - mn);
        ps += p;
        unsigned int lowb = st * 32 + lo4 * 2;
        unsigned int addr = r * 128 + ((((lowb >> 4) ^ (r & 7)) << 4) | (lowb & 15));
        *(unsigned short*)(Plds + addr) = f2bf(p);
      }
      ls[reg] = ls[reg] * corr + ps;
#pragma unroll
      for (int dt = 0; dt < 8; dt++) o_acc[dt][reg] *= corr;
    }

    // O += P @ V   (P via per-wave LDS, V^T gives contiguous B-fragments)
#pragma unroll
    for (int kk = 0; kk < 2; kk++) {
      int cp = kk * 4 + hi4;
      short8 pa = *(const short8*)(Plds + lo4 * 128 + ((cp ^ (lo4 & 7)) << 4));
#pragma unroll
      for (int dt = 0; dt < 8; dt++) {
        int d = dt * 16 + lo4;
        short8 bvf = *(const short8*)(Vlds + d * 128 + ((cp ^ (d & 7)) << 4));
        o_acc[dt] = MFMA16(pa, bvf, o_acc[dt]);
      }
    }
    __syncthreads();
  }

  // normalize: row-sum reduce across the 16-lane group, then write fp32
#pragma unroll
  for (int reg = 0; reg < 4; reg++) {
    float t = ls[reg];
    t += __shfl_xor(t, 1);
    t += __shfl_xor(t, 2);
    t += __shfl_xor(t, 4);
    t += __shfl_xor(t, 8);
    ls[reg] = 4.0f / t;  // NUM_BLOCKS / denom
  }
#pragma unroll
  for (int dt = 0; dt < 8; dt++)
#pragma unroll
    for (int reg = 0; reg < 4; reg++) {
      int r = b * L_ + qt * 64 + w * 16 + hi4 * 4 + reg;
      out[(size_t)r * DK_ + dt * 16 + lo4] = o_acc[dt][reg] * ls[reg];
    }
}

// ---------------------------------------------------------------------------
extern "C" void kernel_launch(void* const* d_in, const int* in_sizes, int n_in,
                              void* d_out, int out_size, void* d_ws, size_t ws_size,
                              hipStream_t stream) {
  const float* x  = (const float*)d_in[0];
  const float* Wq = (const float*)d_in[1];
  const float* bq = (const float*)d_in[2];
  const float* Wk = (const float*)d_in[3];
  const float* bk = (const float*)d_in[4];
  const float* Wv = (const float*)d_in[5];
  const float* bv = (const float*)d_in[6];
  float* out = (float*)d_out;

  // workspace layout (bf16 elems): xb | wb(3x128x1024) | qb | kb | vt  (~45 MB)
  unsigned short* xb = (unsigned short*)d_ws;
  unsigned short* wb = xb + (size_t)B_ * L_ * DM_;
  unsigned short* qb = wb + (size_t)3 * DK_ * DM_;
  unsigned short* kb = qb + (size_t)B_ * L_ * DK_;
  unsigned short* vt = kb + (size_t)B_ * L_ * DK_;

  cvt_kernel<<<(B_ * L_ * DM_) / 8 / 256, 256, 0, stream>>>(x, xb, (B_ * L_ * DM_) / 8);
  cvt_kernel<<<(DK_ * DM_) / 8 / 256, 256, 0, stream>>>(Wq, wb, (DK_ * DM_) / 8);
  cvt_kernel<<<(DK_ * DM_) / 8 / 256, 256, 0, stream>>>(Wk, wb + DK_ * DM_, (DK_ * DM_) / 8);
  cvt_kernel<<<(DK_ * DM_) / 8 / 256, 256, 0, stream>>>(Wv, wb + 2 * DK_ * DM_, (DK_ * DM_) / 8);

  proj_kernel<<<dim3(128, 3), 256, 0, stream>>>(xb, wb, bq, bk, bv, qb, kb, vt, out);
  attn_kernel<<<dim3(64, 4), 256, 0, stream>>>(qb, kb, vt, out);
}

// Round 4
// 228.125 us; speedup vs baseline: 1.3671x; 1.3671x over previous
//
#include <hip/hip_runtime.h>

// Problem constants
#define B_   4
#define L_   4096
#define DM_  1024
#define DK_  128
#define NSPLIT 4            // KV splits in attention (16 tiles of 64 keys each)
#define OUT_K_OFF 2097152   // B*L*DK
#define OUT_V_OFF 4194304   // 2*B*L*DK

typedef __attribute__((ext_vector_type(4))) float f32x4;
typedef __attribute__((ext_vector_type(8))) short short8;

__device__ __forceinline__ unsigned short f2bf(float f) {
  union { float f; unsigned int u; } v; v.f = f;
  unsigned int u = v.u;
  u += 0x7FFFu + ((u >> 16) & 1u);   // RNE
  return (unsigned short)(u >> 16);
}
__device__ __forceinline__ float bf2f(unsigned short u) {
  union { unsigned int i; float f; } v; v.i = ((unsigned int)u) << 16; return v.f;
}

// async global->LDS, 16B per lane. LDS dest = wave-uniform base + lane*16.
#define ASYNC16(gsrc, ldst)                                                          \
  __builtin_amdgcn_global_load_lds(                                                  \
      (const __attribute__((address_space(1))) unsigned int*)(gsrc),                 \
      (__attribute__((address_space(3))) unsigned int*)(ldst), 16, 0, 0)

#define MFMA16(a, b, c) __builtin_amdgcn_mfma_f32_16x16x32_bf16((a), (b), (c), 0, 0, 0)

// ---------------------------------------------------------------------------
// Kernel 0a: fp32 -> bf16 bulk convert (x)
// ---------------------------------------------------------------------------
__global__ __launch_bounds__(256) void cvt_kernel(const float* __restrict__ s,
                                                  unsigned short* __restrict__ d,
                                                  int n8) {
  int i = blockIdx.x * 256 + threadIdx.x;
  if (i >= n8) return;
  const f32x4* p = (const f32x4*)(s + (size_t)i * 8);
  f32x4 a = p[0], b = p[1];
  short8 r;
  r[0] = (short)f2bf(a[0]); r[1] = (short)f2bf(a[1]);
  r[2] = (short)f2bf(a[2]); r[3] = (short)f2bf(a[3]);
  r[4] = (short)f2bf(b[0]); r[5] = (short)f2bf(b[1]);
  r[6] = (short)f2bf(b[2]); r[7] = (short)f2bf(b[3]);
  *(short8*)(d + (size_t)i * 8) = r;
}

// Kernel 0b: fused cvt of the 3 weight matrices. grid (64, 3).
__global__ __launch_bounds__(256) void cvtw_kernel(const float* __restrict__ Wq,
                                                   const float* __restrict__ Wk,
                                                   const float* __restrict__ Wv,
                                                   unsigned short* __restrict__ wb) {
  const float* s = (blockIdx.y == 0) ? Wq : (blockIdx.y == 1) ? Wk : Wv;
  unsigned short* d = wb + (size_t)blockIdx.y * (DK_ * DM_);
  int i = blockIdx.x * 256 + threadIdx.x;   // 64*256 = 16384 = (128*1024)/8
  const f32x4* p = (const f32x4*)(s + (size_t)i * 8);
  f32x4 a = p[0], b = p[1];
  short8 r;
  r[0] = (short)f2bf(a[0]); r[1] = (short)f2bf(a[1]);
  r[2] = (short)f2bf(a[2]); r[3] = (short)f2bf(a[3]);
  r[4] = (short)f2bf(b[0]); r[5] = (short)f2bf(b[1]);
  r[6] = (short)f2bf(b[2]); r[7] = (short)f2bf(b[3]);
  *(short8*)(d + (size_t)i * 8) = r;
}

// ---------------------------------------------------------------------------
// Kernel 1: projection GEMM, 64-row tiles for occupancy.
// out_tile[64][128] = x_tile @ W^T + b.  grid = (256 m-tiles, 3 weights),
// 3 blocks/CU. LDS: A 8KB + B 16KB = 24KB, XOR-swizzled rows (128B).
// wt==0 -> Q bf16 (ws); wt==1 -> K bf16 (ws) + K fp32 (out);
// wt==2 -> V fp32 (out) + V^T bf16 (ws, via LDS transpose).
// ---------------------------------------------------------------------------
__global__ __launch_bounds__(256) void proj_kernel(
    const unsigned short* __restrict__ xb,   // [B*L][1024] bf16
    const unsigned short* __restrict__ wb,   // [3][128][1024] bf16
    const float* __restrict__ bias_q, const float* __restrict__ bias_k,
    const float* __restrict__ bias_v,
    unsigned short* __restrict__ qb,         // [B*L][128] bf16
    unsigned short* __restrict__ kb,         // [B*L][128] bf16
    unsigned short* __restrict__ vt,         // [B][128][L] bf16 (V transposed)
    float* __restrict__ out) {
  __shared__ __align__(16) char smem[24576];  // A 8KB | B 16KB ; T reuse 18KB
  char* Alds = smem;            // [64 rows][128B] swizzled
  char* Blds = smem + 8192;     // [128 rows][128B] swizzled

  const int tid  = threadIdx.x;
  const int w    = tid >> 6;
  const int lane = tid & 63;
  const int lo4  = lane & 15, hi4 = lane >> 4;
  const int wm   = w >> 1, wn = w & 1;        // wave -> 32x64 quadrant
  const int mt   = blockIdx.x;   // 0..255
  const int wt   = blockIdx.y;   // 0..2
  const int r0   = mt * 64;
  const unsigned short* wsrc = wb + (size_t)wt * (DK_ * DM_);

  f32x4 acc[2][4];
#pragma unroll
  for (int i = 0; i < 2; i++)
#pragma unroll
    for (int j = 0; j < 4; j++) acc[i][j] = (f32x4){0.f, 0.f, 0.f, 0.f};

  for (int kt = 0; kt < 16; ++kt) {
    const int kc0 = kt * 64;
    // stage x tile [64][64] (2 loads/lane) and W tile [128][64] (4 loads/lane)
#pragma unroll
    for (int j = 0; j < 2; ++j) {
      unsigned int o   = (unsigned)(w * 2048 + j * 1024 + lane * 16);
      unsigned int row = o >> 7;
      unsigned int cl  = ((o >> 4) & 7) ^ (row & 7);
      ASYNC16(xb + ((size_t)(r0 + row) * DM_ + kc0 + cl * 8), Alds + w * 2048 + j * 1024);
    }
#pragma unroll
    for (int j = 0; j < 4; ++j) {
      unsigned int o   = (unsigned)(w * 4096 + j * 1024 + lane * 16);
      unsigned int row = o >> 7;
      unsigned int cl  = ((o >> 4) & 7) ^ (row & 7);
      ASYNC16(wsrc + ((size_t)row * DM_ + kc0 + cl * 8), Blds + w * 4096 + j * 1024);
    }
    __syncthreads();
#pragma unroll
    for (int kk = 0; kk < 2; ++kk) {
      short8 af[2], bf[4];
#pragma unroll
      for (int mi = 0; mi < 2; mi++) {
        int row = wm * 32 + mi * 16 + lo4;
        int c   = kk * 4 + hi4;
        af[mi]  = *(const short8*)(Alds + row * 128 + (((c ^ (row & 7))) << 4));
      }
#pragma unroll
      for (int ni = 0; ni < 4; ni++) {
        int col = wn * 64 + ni * 16 + lo4;
        int c   = kk * 4 + hi4;
        bf[ni]  = *(const short8*)(Blds + col * 128 + (((c ^ (col & 7))) << 4));
      }
#pragma unroll
      for (int mi = 0; mi < 2; mi++)
#pragma unroll
        for (int ni = 0; ni < 4; ni++)
          acc[mi][ni] = MFMA16(af[mi], bf[ni], acc[mi][ni]);
    }
    __syncthreads();
  }

  const float* bias = (wt == 0) ? bias_q : (wt == 1) ? bias_k : bias_v;
  float bv4[4];
#pragma unroll
  for (int ni = 0; ni < 4; ni++) bv4[ni] = bias[wn * 64 + ni * 16 + lo4];

  const int b_idx = r0 >> 12;      // batch
  const int l0    = r0 & 4095;     // l within batch

  if (wt != 2) {
    unsigned short* dstb = (wt == 0) ? qb : kb;
#pragma unroll
    for (int mi = 0; mi < 2; mi++)
#pragma unroll
      for (int ni = 0; ni < 4; ni++)
#pragma unroll
        for (int reg = 0; reg < 4; reg++) {
          int r   = wm * 32 + mi * 16 + hi4 * 4 + reg;
          int c   = wn * 64 + ni * 16 + lo4;
          float v = acc[mi][ni][reg] + bv4[ni];
          dstb[(size_t)(r0 + r) * DK_ + c] = f2bf(v);
          if (wt == 1) out[OUT_K_OFF + (size_t)(r0 + r) * DK_ + c] = v;
        }
  } else {
    // V: fp32 to out, then LDS transpose -> vt (bf16, [d][l])
    char* T = smem;  // [128 d][144 bytes] (64 l bf16 + 16B pad)
#pragma unroll
    for (int mi = 0; mi < 2; mi++)
#pragma unroll
      for (int ni = 0; ni < 4; ni++)
#pragma unroll
        for (int reg = 0; reg < 4; reg++) {
          int r   = wm * 32 + mi * 16 + hi4 * 4 + reg;
          int c   = wn * 64 + ni * 16 + lo4;
          float v = acc[mi][ni][reg] + bv4[ni];
          out[OUT_V_OFF + (size_t)(r0 + r) * DK_ + c] = v;
          *(unsigned short*)(T + c * 144 + r * 2) = f2bf(v);
        }
    __syncthreads();
#pragma unroll
    for (int i = 0; i < 4; ++i) {
      int q = tid + i * 256;          // 0..1023
      int d = q >> 3, lg = q & 7;
      short8 s8 = *(const short8*)(T + d * 144 + lg * 16);
      *(short8*)(vt + ((size_t)(b_idx * DK_ + d) * L_ + l0 + lg * 8)) = s8;
    }
  }
}

// ---------------------------------------------------------------------------
// Kernel 2: flash attention with 4-way KV split (occupancy: 1024 blocks =
// 4 blocks/CU at 40KB LDS). grid = (L/64, B, NSPLIT). Each split handles 16
// KV tiles of 64 keys and writes unnormalized O (bf16, at its own running
// max) + per-row (m, l) partials. Online softmax fp32, exp2 domain.
// ---------------------------------------------------------------------------
__global__ __launch_bounds__(256) void attn_kernel(
    const unsigned short* __restrict__ qb, const unsigned short* __restrict__ kb,
    const unsigned short* __restrict__ vt,
    unsigned short* __restrict__ Opart,   // [NSPLIT][B*L][128] bf16
    float* __restrict__ ml) {             // [NSPLIT][B*L][2] f32
  __shared__ __align__(16) char smem[40960];  // K 16KB | Vt 16KB | P 4x2KB
  char* Klds = smem;
  char* Vlds = smem + 16384;

  const int tid  = threadIdx.x;
  const int w    = tid >> 6;
  const int lane = tid & 63;
  const int lo4  = lane & 15, hi4 = lane >> 4;
  char* Plds = smem + 32768 + w * 2048;

  const int qt = blockIdx.x;  // 0..63
  const int b  = blockIdx.y;  // 0..3
  const int sp = blockIdx.z;  // 0..NSPLIT-1

  // Q fragments (16 rows x 128 d) held in registers for the whole kernel
  short8 aq[4];
  {
    const unsigned short* qp =
        qb + ((size_t)(b * L_ + qt * 64 + w * 16 + lo4) * DK_ + hi4 * 8);
#pragma unroll
    for (int kc = 0; kc < 4; kc++) aq[kc] = *(const short8*)(qp + kc * 32);
  }

  f32x4 o_acc[8];
#pragma unroll
  for (int dt = 0; dt < 8; dt++) o_acc[dt] = (f32x4){0.f, 0.f, 0.f, 0.f};
  float m[4]  = {-__builtin_inff(), -__builtin_inff(), -__builtin_inff(), -__builtin_inff()};
  float ls[4] = {0.f, 0.f, 0.f, 0.f};
  const float SC = 0.08838834764831845f * 1.4426950408889634f;  // 1/sqrt(128)*log2(e)

  for (int t = sp * 16; t < sp * 16 + 16; ++t) {
    // stage K tile (64x128) and Vt tile (128x64), both bf16 swizzled
#pragma unroll
    for (int j = 0; j < 4; ++j) {
      unsigned int o = (unsigned)(w * 1024 + j * 4096 + lane * 16);
      unsigned int krow = o >> 8;
      unsigned int kcl  = ((o >> 4) & 15) ^ (krow & 7);
      ASYNC16(kb + ((size_t)(b * L_ + t * 64 + krow) * DK_ + kcl * 8),
              Klds + w * 1024 + j * 4096);
      unsigned int d   = o >> 7;
      unsigned int vcl = ((o >> 4) & 7) ^ (d & 7);
      ASYNC16(vt + ((size_t)(b * DK_ + d) * L_ + t * 64 + vcl * 8),
              Vlds + w * 1024 + j * 4096);
    }
    __syncthreads();

    // S = Q K^T  (4 key-subtiles of 16)
    f32x4 s[4];
#pragma unroll
    for (int st = 0; st < 4; st++) s[st] = (f32x4){0.f, 0.f, 0.f, 0.f};
#pragma unroll
    for (int st = 0; st < 4; st++) {
      int key = st * 16 + lo4;
#pragma unroll
      for (int kc = 0; kc < 4; kc++) {
        int c = kc * 4 + hi4;
        short8 bkf = *(const short8*)(Klds + key * 256 + ((c ^ (key & 7)) << 4));
        s[st] = MFMA16(aq[kc], bkf, s[st]);
      }
    }

    // online softmax (rows = hi4*4+reg, lane owns cols st*16+lo4)
#pragma unroll
    for (int reg = 0; reg < 4; reg++) {
      float pm = fmaxf(fmaxf(s[0][reg], s[1][reg]), fmaxf(s[2][reg], s[3][reg]));
      pm = fmaxf(pm, __shfl_xor(pm, 1));
      pm = fmaxf(pm, __shfl_xor(pm, 2));
      pm = fmaxf(pm, __shfl_xor(pm, 4));
      pm = fmaxf(pm, __shfl_xor(pm, 8));
      pm *= SC;
      float mn   = fmaxf(m[reg], pm);
      float corr = exp2f(m[reg] - mn);
      m[reg]     = mn;
      float ps   = 0.f;
      int   r    = hi4 * 4 + reg;
#pragma unroll
      for (int st = 0; st < 4; st++) {
        float p = exp2f(s[st][reg] * SC - mn);
        ps += p;
        unsigned int lowb = st * 32 + lo4 * 2;
        unsigned int addr = r * 128 + ((((lowb >> 4) ^ (r & 7)) << 4) | (lowb & 15));
        *(unsigned short*)(Plds + addr) = f2bf(p);
      }
      ls[reg] = ls[reg] * corr + ps;
#pragma unroll
      for (int dt = 0; dt < 8; dt++) o_acc[dt][reg] *= corr;
    }

    // O += P @ V   (P via per-wave LDS, V^T gives contiguous B-fragments)
#pragma unroll
    for (int kk = 0; kk < 2; kk++) {
      int cp = kk * 4 + hi4;
      short8 pa = *(const short8*)(Plds + lo4 * 128 + ((cp ^ (lo4 & 7)) << 4));
#pragma unroll
      for (int dt = 0; dt < 8; dt++) {
        int d = dt * 16 + lo4;
        short8 bvf = *(const short8*)(Vlds + d * 128 + ((cp ^ (d & 7)) << 4));
        o_acc[dt] = MFMA16(pa, bvf, o_acc[dt]);
      }
    }
    __syncthreads();
  }

  // epilogue: reduce l across the 16-lane group, store partials
  float lt[4];
#pragma unroll
  for (int reg = 0; reg < 4; reg++) {
    float t = ls[reg];
    t += __shfl_xor(t, 1);
    t += __shfl_xor(t, 2);
    t += __shfl_xor(t, 4);
    t += __shfl_xor(t, 8);
    lt[reg] = t;
  }
  const size_t rowbase = (size_t)(sp * B_ + b) * L_ + qt * 64 + w * 16;
  if (lo4 == 0) {
#pragma unroll
    for (int reg = 0; reg < 4; reg++) {
      size_t idx = rowbase + hi4 * 4 + reg;
      ml[idx * 2 + 0] = m[reg];
      ml[idx * 2 + 1] = lt[reg];
    }
  }
#pragma unroll
  for (int dt = 0; dt < 8; dt++)
#pragma unroll
    for (int reg = 0; reg < 4; reg++)
      Opart[(rowbase + hi4 * 4 + reg) * 128 + dt * 16 + lo4] = f2bf(o_acc[dt][reg]);
}

// ---------------------------------------------------------------------------
// Kernel 3: combine the NSPLIT partials.  out = 4 * (sum_s O_s*w_s) / (sum_s
// l_s*w_s), w_s = 2^(m_s - M).  grid (64, 4), 256 threads, memory-bound.
// ---------------------------------------------------------------------------
__global__ __launch_bounds__(256) void combine_kernel(
    const unsigned short* __restrict__ Opart, const float* __restrict__ ml,
    float* __restrict__ out) {
  const int qt = blockIdx.x, b = blockIdx.y, tid = threadIdx.x;
#pragma unroll
  for (int i = 0; i < 4; ++i) {
    int idx = i * 256 + tid;          // 0..1023
    int row = idx >> 4, cg = idx & 15;
    size_t grow = (size_t)b * L_ + qt * 64 + row;
    float ms[NSPLIT], lv[NSPLIT], M = -__builtin_inff();
#pragma unroll
    for (int s = 0; s < NSPLIT; s++) {
      size_t p = ((size_t)s * B_ * L_ + grow) * 2;
      ms[s] = ml[p]; lv[s] = ml[p + 1];
      M = fmaxf(M, ms[s]);
    }
    float acc[8] = {0.f, 0.f, 0.f, 0.f, 0.f, 0.f, 0.f, 0.f};
    float lsum = 0.f;
#pragma unroll
    for (int s = 0; s < NSPLIT; s++) {
      float wgt = exp2f(ms[s] - M);
      lsum += lv[s] * wgt;
      short8 v = *(const short8*)&Opart[((size_t)(s * B_ + b) * L_ + qt * 64 + row) * 128 + cg * 8];
#pragma unroll
      for (int j = 0; j < 8; j++) acc[j] += bf2f((unsigned short)v[j]) * wgt;
    }
    float sc = 4.0f / lsum;   // NUM_BLOCKS / denom
    f32x4 o0 = {acc[0] * sc, acc[1] * sc, acc[2] * sc, acc[3] * sc};
    f32x4 o1 = {acc[4] * sc, acc[5] * sc, acc[6] * sc, acc[7] * sc};
    float* dst = out + grow * 128 + cg * 8;
    *(f32x4*)dst = o0;
    *(f32x4*)(dst + 4) = o1;
  }
}

// ---------------------------------------------------------------------------
extern "C" void kernel_launch(void* const* d_in, const int* in_sizes, int n_in,
                              void* d_out, int out_size, void* d_ws, size_t ws_size,
                              hipStream_t stream) {
  const float* x  = (const float*)d_in[0];
  const float* Wq = (const float*)d_in[1];
  const float* bq = (const float*)d_in[2];
  const float* Wk = (const float*)d_in[3];
  const float* bk = (const float*)d_in[4];
  const float* Wv = (const float*)d_in[5];
  const float* bv = (const float*)d_in[6];
  float* out = (float*)d_out;

  // workspace layout (bf16 elems): xb | wb(3x128x1024) | qb | kb | vt (~51 MB)
  // After proj completes, xb is dead -> reuse its region for attention
  // partials (Opart 16.8MB + ml 0.5MB < 33.5MB). Single-stream ordering makes
  // this safe.
  unsigned short* xb = (unsigned short*)d_ws;
  unsigned short* wb = xb + (size_t)B_ * L_ * DM_;
  unsigned short* qb = wb + (size_t)3 * DK_ * DM_;
  unsigned short* kb = qb + (size_t)B_ * L_ * DK_;
  unsigned short* vt = kb + (size_t)B_ * L_ * DK_;
  unsigned short* Opart = xb;                                   // [NSPLIT][B*L][128] bf16
  float* ml = (float*)(xb + (size_t)NSPLIT * B_ * L_ * DK_);    // [NSPLIT][B*L][2] f32

  cvt_kernel<<<(B_ * L_ * DM_) / 8 / 256, 256, 0, stream>>>(x, xb, (B_ * L_ * DM_) / 8);
  cvtw_kernel<<<dim3(64, 3), 256, 0, stream>>>(Wq, Wk, Wv, wb);

  proj_kernel<<<dim3(256, 3), 256, 0, stream>>>(xb, wb, bq, bk, bv, qb, kb, vt, out);
  attn_kernel<<<dim3(64, B_, NSPLIT), 256, 0, stream>>>(qb, kb, vt, Opart, ml);
  combine_kernel<<<dim3(64, B_), 256, 0, stream>>>(Opart, ml, out);
}